// Round 3
// baseline (6337.346 us; speedup 1.0000x reference)
//
#include <hip/hip_runtime.h>
#include <hip/hip_fp16.h>
#include <cstdint>

#define TT 128   // time steps (= bucket_size)
#define BB 128   // batch
#define II 512   // input dim
#define HH 512   // hidden dim
#define DD 1024  // I + H
#define NC 513   // H + 1
#define NPAD 520 // row pitch for lnXW / vbuf (f16)
#define NT 36    // n-tiles of 16 in GEMM (576 padded cols)
#define EPSL 1e-5f

typedef _Float16 h2v __attribute__((ext_vector_type(2)));
typedef _Float16 h8v __attribute__((ext_vector_type(8)));
typedef float    f4v __attribute__((ext_vector_type(4)));

__device__ __forceinline__ ushort f2h(float f){
  return __builtin_bit_cast(ushort, __float2half(f));
}
__device__ __forceinline__ float h2f(ushort s){
  return __half2float(__builtin_bit_cast(__half, s));
}
__device__ __forceinline__ float hsig(float x){
  return fminf(fmaxf(0.2f * x + 0.5f, 0.f), 1.f);
}
__device__ __forceinline__ float ftanh(float x){
  float e = __expf(2.f * x);
  return 1.f - 2.f * __builtin_amdgcn_rcpf(e + 1.f);
}
__device__ __forceinline__ float fdot2f(uint u, uint t, float acc){
#if __has_builtin(__builtin_amdgcn_fdot2)
  return __builtin_amdgcn_fdot2(__builtin_bit_cast(h2v, u), __builtin_bit_cast(h2v, t), acc, false);
#else
  h2v a = __builtin_bit_cast(h2v, u), b = __builtin_bit_cast(h2v, t);
  acc = fmaf((float)a[0], (float)b[0], acc);
  return fmaf((float)a[1], (float)b[1], acc);
#endif
}

// ---------------- pre-pack W / U into MFMA B-fragment order (f16) ----------
__global__ void prepack_B(const float* __restrict__ src, ushort* __restrict__ dst){
  int idx = blockIdx.x * 256 + threadIdx.x;
  if (idx >= 128 * NT * 16 * 8) return;
  int kl = idx & 7;
  int ni = (idx >> 3) & 15;
  int nt = (idx >> 7) % NT;
  int kc = idx / (NT * 16 * 8);
  int k = kc * 8 + kl;
  int n = nt * 16 + ni;
  float v = (n < NC) ? src[k * NC + n] : 0.f;
  dst[idx] = f2h(v);
}

// ---------------- pre-pack U_hi for register-resident GEMV slices ----------
// Upkr uint idx = ((c*4 + kq)*16 + j)*4 + p  holds f16 pair
//   (U[II + kq*128 + j*8 + 2p][c], U[II + kq*128 + j*8 + 2p + 1][c])
__global__ void prepack_Ureg(const float* __restrict__ U, uint* __restrict__ Upkr,
                             ushort* __restrict__ ucol){
  int idx = blockIdx.x * 256 + threadIdx.x;
  if (idx < 512 * 4 * 16 * 4){
    int p  = idx & 3;
    int j  = (idx >> 2) & 15;
    int kq = (idx >> 6) & 3;
    int c  = idx >> 8;
    int k  = kq * 128 + j * 8 + 2 * p;
    ushort lo = f2h(U[(size_t)(II + k) * NC + c]);
    ushort hi = f2h(U[(size_t)(II + k + 1) * NC + c]);
    Upkr[idx] = (uint)lo | ((uint)hi << 16);
  }
  if (idx < 512) ucol[idx] = f2h(U[(size_t)(II + idx) * NC + (NC - 1)]);
}

// ---------------- fused GEMM (+ optional row-LayerNorm), f16 MFMA ----------
__global__ __launch_bounds__(1024) void gemm_ln(
    const float* __restrict__ A, int amode, int ksteps,
    const ushort* __restrict__ Bpk, ushort* __restrict__ out,
    int do_ln, const float* __restrict__ gam, const float* __restrict__ bet,
    const float* __restrict__ bias)
{
  __shared__ ushort As[64][40];
  __shared__ float red[4][4][16][2];
  int tid = threadIdx.x;
  int lane = tid & 63, wid = tid >> 6;
  int quad = lane >> 4, l16 = lane & 15;
  int wm = wid >> 2, wn = wid & 3;
  int blk = blockIdx.x;

  f4v acc[9];
#pragma unroll
  for (int i = 0; i < 9; i++) acc[i] = (f4v){0.f, 0.f, 0.f, 0.f};

  int arow = tid >> 4;
  int acp  = tid & 15;
  int r = blk * 64 + arow;
  const float* aptr;
  if (amode == 0){ int t = r >> 7, b = r & 127; aptr = A + ((size_t)(b * TT + t)) * II + acp * 2; }
  else           { aptr = A + (size_t)r * DD + acp * 2; }

  for (int ks = 0; ks < ksteps; ks++){
    __syncthreads();
    float2 a2 = *(const float2*)(aptr + ks * 32);
    uint pk = (uint)f2h(a2.x) | ((uint)f2h(a2.y) << 16);
    *(uint*)&As[arow][acp * 2] = pk;
    __syncthreads();
    h8v af = *(const h8v*)&As[wm * 16 + l16][quad * 8];
    int kc = ks * 4 + quad;
    const h8v* bp = (const h8v*)Bpk + (size_t)kc * (NT * 16) + l16;
#pragma unroll
    for (int i = 0; i < 9; i++){
      h8v bf = bp[(wn * 9 + i) * 16];
      acc[i] = __builtin_amdgcn_mfma_f32_16x16x32_f16(af, bf, acc[i], 0, 0, 0);
    }
  }

  int rowbase = blk * 64 + wm * 16 + quad * 4;
  if (do_ln){
    float s1[4], s2[4];
#pragma unroll
    for (int g = 0; g < 4; g++){
      float a = 0.f, q = 0.f;
#pragma unroll
      for (int i = 0; i < 9; i++){ float v = acc[i][g]; a += v; q += v * v; }
#pragma unroll
      for (int m = 1; m < 16; m <<= 1){ a += __shfl_xor(a, m, 64); q += __shfl_xor(q, m, 64); }
      s1[g] = a; s2[g] = q;
    }
    if (l16 == 0){
#pragma unroll
      for (int g = 0; g < 4; g++){
        red[wm][wn][quad * 4 + g][0] = s1[g];
        red[wm][wn][quad * 4 + g][1] = s2[g];
      }
    }
    __syncthreads();
#pragma unroll
    for (int g = 0; g < 4; g++){
      int rr = quad * 4 + g;
      float S1 = red[wm][0][rr][0] + red[wm][1][rr][0] + red[wm][2][rr][0] + red[wm][3][rr][0];
      float S2 = red[wm][0][rr][1] + red[wm][1][rr][1] + red[wm][2][rr][1] + red[wm][3][rr][1];
      float mean = S1 * (1.f / 513.f);
      float var  = S2 * (1.f / 513.f) - mean * mean;
      float inv  = 1.f / (sqrtf(var + EPSL) + EPSL);
      size_t rg = (size_t)(rowbase + g);
#pragma unroll
      for (int i = 0; i < 9; i++){
        int n = wn * 144 + i * 16 + l16;
        if (n < NC){
          float val = gam[n] * ((acc[i][g] - mean) * inv) + bet[n] + bias[n];
          out[rg * NPAD + n] = f2h(val);
        }
      }
    }
  } else {
#pragma unroll
    for (int g = 0; g < 4; g++){
      size_t rg = (size_t)(rowbase + g);
#pragma unroll
      for (int i = 0; i < 9; i++){
        int n = wn * 144 + i * 16 + l16;
        if (n < NC) out[rg * NPAD + n] = f2h(acc[i][g]);
      }
    }
  }
}

// ---------------- 4-way column-split sequential recurrence -----------------
// 256 blocks: group g = blockIdx&63 owns batch rows b0=2g, b1=2g+1;
// slice s = blockIdx>>6 owns v-cols [128s,128s+128) (+col 512 for s==3)
// and h-dims [256s, 256s+256). U-slice lives in 64 VGPRs/thread.
// Per-timestep v exchange via agent-scope atomics + per-group flags.
__global__ __launch_bounds__(512, 2) void rnn_layer(
    int layer,
    const float* __restrict__ x,
    float* __restrict__ h_seq,
    const ushort* __restrict__ lnXW,
    ushort* __restrict__ vbuf,
    float* __restrict__ fkbuf,
    float* __restrict__ hvbuf,
    const uint* __restrict__ Upkr,
    const ushort* __restrict__ ucol,
    const int* __restrict__ mask,
    const float* __restrict__ gam1, const float* __restrict__ bet1,
    const float* __restrict__ bias,
    float* __restrict__ vx,      // [2][BB][520] f32 exchange slots
    int* __restrict__ flags,     // [64][4] padded 64B apart
    float* __restrict__ out)
{
  __shared__ float  vfull[2][520];
  __shared__ ushort tanhvh[2][512];
  __shared__ float  ypart[3][128][2];
  __shared__ float  statred[8][2];
  __shared__ float  p512red[8][2];
  __shared__ float  shg[2][2];          // [row][0]=s_col0 [1]=sum2_col0
  __shared__ float  fkp_l[2][TT + 1];
  __shared__ float  hvp_l[2][TT];
  __shared__ unsigned char mkq[2][TT];

  const int tid  = threadIdx.x;
  const int g    = blockIdx.x & 63;
  const int s    = blockIdx.x >> 6;
  const int b0   = 2 * g, b1 = 2 * g + 1;
  const int lane = tid & 63, wid = tid >> 6;
  const int c_l  = tid & 127;           // GEMV local col
  const int kq   = tid >> 7;            // GEMV k-quarter (0..3)
  const int cg   = s * 128 + c_l;       // GEMV global col
  const int rH   = tid >> 8;            // h-update row (0/1)
  const int dH   = s * 256 + (tid & 255); // h-update dim
  const int bH   = 2 * g + rH;
  const int base = layer * TT;

  // ---- one-time setup ----
  if (tid < TT){
    mkq[0][tid] = (unsigned char)(mask[b0 * TT + tid] > 0);
    mkq[1][tid] = (unsigned char)(mask[b1 * TT + tid] > 0);
    if (layer == 0){
      fkp_l[0][tid] = 0.f; fkp_l[1][tid] = 0.f;
      hvp_l[0][tid] = 1.f; hvp_l[1][tid] = 1.f;
    } else {
      fkp_l[0][tid] = fkbuf[tid * BB + b0];
      fkp_l[1][tid] = fkbuf[tid * BB + b1];
      hvp_l[0][tid] = hvbuf[tid * BB + b0];
      hvp_l[1][tid] = hvbuf[tid * BB + b1];
    }
  }
  if (tid == 0){ fkp_l[0][TT] = 0.f; fkp_l[1][TT] = 0.f; }
  vfull[0][tid] = 0.f; vfull[1][tid] = 0.f;
  if (tid < 8){ vfull[0][512 + tid] = 0.f; vfull[1][512 + tid] = 0.f; }

  float g1n = gam1[tid], b1n = bet1[tid];
  float g1_512 = 0.f, b1_512 = 0.f;
  if (tid == 0){ g1_512 = gam1[512]; b1_512 = bet1[512]; }
  ushort ucolr = (s == 3) ? ucol[tid] : (ushort)0;

  // register-resident U slice: 16 uint4 = 128 k-values for col cg, quarter kq
  uint4 ureg[16];
  {
    const uint4* uptr = (const uint4*)Upkr + ((size_t)cg * 4 + kq) * 16;
#pragma unroll
    for (int j = 0; j < 16; j++) ureg[j] = uptr[j];
  }

  float hreg = 0.f;                       // owned h component
  float fk_c0 = 0.f, hv_c0 = 0.f, fk_c1 = 0.f, hv_c1 = 0.f;
  const int k0 = kq * 128;

  __syncthreads();

  for (int t = 0; t < TT; t++){
    const size_t row0 = (size_t)(t * BB + b0);
    const size_t row1 = (size_t)(t * BB + b1);
    const size_t rowH = (size_t)(t * BB + bH);

    // ---- phase 0: issue independent global loads early ----
    ushort lnx0 = lnXW[row0 * NPAD + tid];
    ushort lnx1 = lnXW[row1 * NPAD + tid];
    float xh;
    if (dH < 512){
      xh = (layer == 0) ? x[((size_t)bH * TT + t) * II + dH]
                        : h_seq[rowH * DD + dH];
    } else {
      xh = (layer == 0) ? 0.f : h_seq[rowH * DD + dH];
    }
    ushort xu0_u = 0, xu1_u = 0;
    if (kq == 0){ xu0_u = vbuf[row0 * NPAD + cg]; xu1_u = vbuf[row1 * NPAD + cg]; }
    ushort lnx512_0 = 0, lnx512_1 = 0, xu512_0 = 0, xu512_1 = 0;
    if (tid == 0){
      lnx512_0 = lnXW[row0 * NPAD + 512];
      lnx512_1 = lnXW[row1 * NPAD + 512];
      if (s == 3){ xu512_0 = vbuf[row0 * NPAD + 512]; xu512_1 = vbuf[row1 * NPAD + 512]; }
    }

    // ---- spin + merge peer v-slices (t>0) ----
    if (tid == 0 && t > 0){
      int target = base + t;
#pragma unroll
      for (int p = 0; p < 4; p++){
        if (p == s) continue;
        while (__hip_atomic_load(&flags[(g * 4 + p) * 16], __ATOMIC_ACQUIRE,
                                 __HIP_MEMORY_SCOPE_AGENT) < target){
          __builtin_amdgcn_s_sleep(1);
        }
      }
    }
    __syncthreads();   // (A)
    if (t > 0){
      const float* vsl = vx + ((size_t)((t - 1) & 1) * BB) * 520;
      if (tid < 384){
        int p  = tid >> 7;
        int ps = p + (p >= s);
        int c  = ps * 128 + (tid & 127);
        vfull[0][c] = __hip_atomic_load(&vsl[(size_t)b0 * 520 + c], __ATOMIC_RELAXED, __HIP_MEMORY_SCOPE_AGENT);
        vfull[1][c] = __hip_atomic_load(&vsl[(size_t)b1 * 520 + c], __ATOMIC_RELAXED, __HIP_MEMORY_SCOPE_AGENT);
      } else if (tid == 384 && s != 3){
        vfull[0][512] = __hip_atomic_load(&vsl[(size_t)b0 * 520 + 512], __ATOMIC_RELAXED, __HIP_MEMORY_SCOPE_AGENT);
        vfull[1][512] = __hip_atomic_load(&vsl[(size_t)b1 * 520 + 512], __ATOMIC_RELAXED, __HIP_MEMORY_SCOPE_AGENT);
      }
    }
    __syncthreads();   // (B)

    // ---- stats: LN over 513 cols per row ----
    {
      int r = rH, i = tid & 255;
      float v0 = vfull[r][i], v1 = vfull[r][256 + i];
      float a = v0 + v1, q = v0 * v0 + v1 * v1;
      if (i == 0){ float e = vfull[r][512]; a += e; q += e * e; }
#pragma unroll
      for (int m = 1; m < 64; m <<= 1){
        a += __shfl_xor(a, m, 64);
        q += __shfl_xor(q, m, 64);
      }
      if (lane == 0){ statred[wid][0] = a; statred[wid][1] = q; }
    }
    __syncthreads();   // (C)
    float S0 = statred[0][0] + statred[1][0] + statred[2][0] + statred[3][0];
    float Q0 = statred[0][1] + statred[1][1] + statred[2][1] + statred[3][1];
    float S1 = statred[4][0] + statred[5][0] + statred[6][0] + statred[7][0];
    float Q1 = statred[4][1] + statred[5][1] + statred[6][1] + statred[7][1];
    float m0 = S0 * (1.f / 513.f);
    float var0 = Q0 * (1.f / 513.f) - m0 * m0;
    float inv0 = __builtin_amdgcn_rcpf(sqrtf(var0 + EPSL) + EPSL);
    float m1 = S1 * (1.f / 513.f);
    float var1 = Q1 * (1.f / 513.f) - m1 * m1;
    float inv1 = __builtin_amdgcn_rcpf(sqrtf(var1 + EPSL) + EPSL);

    // ---- tanh over all 512 core cols (thread tid -> col tid) ----
    {
      float sum2_0 = (vfull[0][tid] - m0) * inv0 * g1n + b1n;
      float sum2_1 = (vfull[1][tid] - m1) * inv1 * g1n + b1n;
      float s_0 = h2f(lnx0) + sum2_0;
      float s_1 = h2f(lnx1) + sum2_1;
      if (tid != 0){
        tanhvh[0][tid - 1] = f2h(ftanh(s_0));
        tanhvh[1][tid - 1] = f2h(ftanh(s_1));
      } else {
        shg[0][0] = s_0; shg[0][1] = sum2_0;
        shg[1][0] = s_1; shg[1][1] = sum2_1;
        float s512_0 = h2f(lnx512_0) + (vfull[0][512] - m0) * inv0 * g1_512 + b1_512;
        float s512_1 = h2f(lnx512_1) + (vfull[1][512] - m1) * inv1 * g1_512 + b1_512;
        tanhvh[0][511] = f2h(ftanh(s512_0));
        tanhvh[1][511] = f2h(ftanh(s512_1));
      }
    }
    __syncthreads();   // (D)

    // ---- gates (redundant on all threads, both rows) ----
    float b0r = bias[0];
    bool mk0 = mkq[0][t] != 0, mk1 = mkq[1][t] != 0;
    bool mk2_0 = (t > 0) && (mkq[0][t - 1] != 0) && !mk0;
    bool mk2_1 = (t > 0) && (mkq[1][t - 1] != 0) && !mk1;
    float ho0, xo0, bo0, ho1, xo1, bo1;
    {
      float fk_both = hsig(shg[0][0]);
      float fk_t1   = hsig(shg[0][1] + b0r);
      float fk = fkp_l[0][t] + (1.f - fkp_l[0][t]) * (fk_c0 * fk_both + (1.f - fk_c0) * fk_t1);
      if (mk2_0) fk = 0.f;
      float fkp = fkp_l[0][t + 1], hvp = hvp_l[0][t];
      ho0 = hv_c0 * fk * (fkp + (1.f - fkp) * (1.f - hvp));
      xo0 = hvp * (1.f - fkp) * (1.f - fk + fk * (1.f - hv_c0));
      bo0 = (1.f - fkp) * fk * hv_c0 * hvp;
      float hv = 1.f - (1.f - ho0) * (1.f - xo0) * (1.f - bo0);
      fk_c0 = mk0 ? fk : fk_c0;
      hv_c0 = mk0 ? hv : hv_c0;
      if (mk2_0) fk_c0 = 0.f;
    }
    {
      float fk_both = hsig(shg[1][0]);
      float fk_t1   = hsig(shg[1][1] + b0r);
      float fk = fkp_l[1][t] + (1.f - fkp_l[1][t]) * (fk_c1 * fk_both + (1.f - fk_c1) * fk_t1);
      if (mk2_1) fk = 0.f;
      float fkp = fkp_l[1][t + 1], hvp = hvp_l[1][t];
      ho1 = hv_c1 * fk * (fkp + (1.f - fkp) * (1.f - hvp));
      xo1 = hvp * (1.f - fkp) * (1.f - fk + fk * (1.f - hv_c1));
      bo1 = (1.f - fkp) * fk * hv_c1 * hvp;
      float hv = 1.f - (1.f - ho1) * (1.f - xo1) * (1.f - bo1);
      fk_c1 = mk1 ? fk : fk_c1;
      hv_c1 = mk1 ? hv : hv_c1;
      if (mk2_1) fk_c1 = 0.f;
    }
    if (layer < 3 && s == 0 && tid == 0){
      fkbuf[t * BB + b0] = fk_c0; hvbuf[t * BB + b0] = hv_c0;
      fkbuf[t * BB + b1] = fk_c1; hvbuf[t * BB + b1] = hv_c1;
    }

    // ---- GEMV: y[cg] partial over k-range [k0,k0+128), both rows ----
    float ya0 = 0.f, ya1 = 0.f;
#pragma unroll
    for (int j = 0; j < 16; j++){
      uint4 u = ureg[j];
      uint4 ta = *(const uint4*)&tanhvh[0][k0 + 8 * j];
      uint4 tb = *(const uint4*)&tanhvh[1][k0 + 8 * j];
      ya0 = fdot2f(u.x, ta.x, ya0); ya0 = fdot2f(u.y, ta.y, ya0);
      ya0 = fdot2f(u.z, ta.z, ya0); ya0 = fdot2f(u.w, ta.w, ya0);
      ya1 = fdot2f(u.x, tb.x, ya1); ya1 = fdot2f(u.y, tb.y, ya1);
      ya1 = fdot2f(u.z, tb.z, ya1); ya1 = fdot2f(u.w, tb.w, ya1);
    }
    if (kq > 0){ ypart[kq - 1][c_l][0] = ya0; ypart[kq - 1][c_l][1] = ya1; }

    // ---- col 512 partial (slice 3) ----
    if (s == 3){
      float uc = h2f(ucolr);
      float p0 = h2f(tanhvh[0][tid]) * uc;
      float p1 = h2f(tanhvh[1][tid]) * uc;
#pragma unroll
      for (int m = 1; m < 64; m <<= 1){
        p0 += __shfl_xor(p0, m, 64);
        p1 += __shfl_xor(p1, m, 64);
      }
      if (lane == 0){ p512red[wid][0] = p0; p512red[wid][1] = p1; }
    }

    // ---- h update (owned dim) ----
    {
      float ho = rH ? ho1 : ho0, xo = rH ? xo1 : xo0, bo = rH ? bo1 : bo0;
      bool mk = rH ? mk1 : mk0;
      float th = (dH >= 512) ? h2f(tanhvh[rH][dH - 512]) : 0.f;
      float nh = ho * hreg + xo * xh + bo * th;
      if (mk) hreg = nh;
      if (layer < 3) h_seq[rowH * DD + dH] = hreg;
      if (layer == 3 && t == TT - 1 && dH >= 512) out[(size_t)bH * HH + (dH - 512)] = hreg;
    }
    __syncthreads();   // (E)

    // ---- v update + publish (kq==0 threads own cols) ----
    float* vsl = vx + ((size_t)(t & 1) * BB) * 520;
    if (kq == 0){
      float y0 = ya0 + ypart[0][c_l][0] + ypart[1][c_l][0] + ypart[2][c_l][0];
      float y1 = ya1 + ypart[0][c_l][1] + ypart[1][c_l][1] + ypart[2][c_l][1];
      float nv0 = ho0 * vfull[0][cg] + xo0 * h2f(xu0_u) + bo0 * y0;
      float nv1 = ho1 * vfull[1][cg] + xo1 * h2f(xu1_u) + bo1 * y1;
      float v0 = mk0 ? nv0 : vfull[0][cg];
      float v1 = mk1 ? nv1 : vfull[1][cg];
      vfull[0][cg] = v0; vfull[1][cg] = v1;
      __hip_atomic_store(&vsl[(size_t)b0 * 520 + cg], v0, __ATOMIC_RELAXED, __HIP_MEMORY_SCOPE_AGENT);
      __hip_atomic_store(&vsl[(size_t)b1 * 520 + cg], v1, __ATOMIC_RELAXED, __HIP_MEMORY_SCOPE_AGENT);
      if (layer < 3){
        vbuf[row0 * NPAD + cg] = f2h(v0);
        vbuf[row1 * NPAD + cg] = f2h(v1);
      }
    }
    if (s == 3 && tid == 0){
      float y512_0 = 0.f, y512_1 = 0.f;
#pragma unroll
      for (int w = 0; w < 8; w++){ y512_0 += p512red[w][0]; y512_1 += p512red[w][1]; }
      float nv0 = ho0 * vfull[0][512] + xo0 * h2f(xu512_0) + bo0 * y512_0;
      float nv1 = ho1 * vfull[1][512] + xo1 * h2f(xu512_1) + bo1 * y512_1;
      float v0 = mk0 ? nv0 : vfull[0][512];
      float v1 = mk1 ? nv1 : vfull[1][512];
      vfull[0][512] = v0; vfull[1][512] = v1;
      __hip_atomic_store(&vsl[(size_t)b0 * 520 + 512], v0, __ATOMIC_RELAXED, __HIP_MEMORY_SCOPE_AGENT);
      __hip_atomic_store(&vsl[(size_t)b1 * 520 + 512], v1, __ATOMIC_RELAXED, __HIP_MEMORY_SCOPE_AGENT);
      if (layer < 3){
        vbuf[row0 * NPAD + 512] = f2h(v0);
        vbuf[row1 * NPAD + 512] = f2h(v1);
      }
    }
    __syncthreads();   // (F) — drains all vx stores (vmcnt) before flag
    if (tid == 0){
      __hip_atomic_store(&flags[(g * 4 + s) * 16], base + t + 1,
                         __ATOMIC_RELEASE, __HIP_MEMORY_SCOPE_AGENT);
    }
  }
}

extern "C" void kernel_launch(void* const* d_in, const int* in_sizes, int n_in,
                              void* d_out, int out_size, void* d_ws, size_t ws_size,
                              hipStream_t stream)
{
  (void)in_sizes; (void)n_in; (void)out_size; (void)ws_size;
  const float* x      = (const float*)d_in[0];
  const int*   mask   = (const int*)d_in[1];
  const float* W      = (const float*)d_in[2];
  const float* U      = (const float*)d_in[3];
  const float* bias   = (const float*)d_in[4];
  const float* gammas = (const float*)d_in[5];
  const float* betas  = (const float*)d_in[6];
  float* out = (float*)d_out;

  char* ws = (char*)d_ws;
  size_t off = 0;
  auto alloc = [&](size_t bytes) -> void* {
    void* p = ws + off;
    off += (bytes + 255) & ~(size_t)255;
    return p;
  };
  float*  h_seq = (float*) alloc((size_t)TT * BB * DD * 4);
  ushort* lnXW  = (ushort*)alloc((size_t)TT * BB * NPAD * 2);
  ushort* vbuf  = (ushort*)alloc((size_t)TT * BB * NPAD * 2);
  float*  fkbuf = (float*) alloc((size_t)TT * BB * 4);
  float*  hvbuf = (float*) alloc((size_t)TT * BB * 4);
  ushort* Wpk   = (ushort*)alloc((size_t)128 * NT * 16 * 8 * 2);
  ushort* Upk   = (ushort*)alloc((size_t)128 * NT * 16 * 8 * 2);
  uint*   Upkr  = (uint*)  alloc((size_t)512 * 4 * 16 * 4 * 4);
  ushort* ucol  = (ushort*)alloc(512 * 2);
  float*  vx    = (float*) alloc((size_t)2 * BB * 520 * 4);
  int*    flags = (int*)   alloc((size_t)64 * 4 * 16 * 4);

  hipMemsetAsync(flags, 0, (size_t)64 * 4 * 16 * 4, stream);

  int npk = 128 * NT * 16 * 8;
  prepack_B<<<dim3((npk + 255) / 256), dim3(256), 0, stream>>>(W, Wpk);
  prepack_B<<<dim3((npk + 255) / 256), dim3(256), 0, stream>>>(U, Upk);
  prepack_Ureg<<<dim3((512 * 4 * 16 * 4 + 255) / 256), dim3(256), 0, stream>>>(U, Upkr, ucol);

  const float* g0 = gammas,      *g1 = gammas + NC;
  const float* be0 = betas,      *be1 = betas + NC;

  gemm_ln<<<dim3(256), dim3(1024), 0, stream>>>(x, 0, 16, Wpk, lnXW, 1, g0, be0, bias);
  gemm_ln<<<dim3(256), dim3(1024), 0, stream>>>(x, 0, 16, Upk, vbuf, 0, g0, be0, bias);
  rnn_layer<<<dim3(256), dim3(512), 0, stream>>>(0, x, h_seq, lnXW, vbuf, fkbuf, hvbuf,
                                                 Upkr, ucol, mask, g1, be1, bias, vx, flags, out);
  for (int d = 1; d < 4; d++){
    gemm_ln<<<dim3(256), dim3(1024), 0, stream>>>(h_seq, 1, 32, Wpk, lnXW, 1, g0, be0, bias);
    rnn_layer<<<dim3(256), dim3(512), 0, stream>>>(d, x, h_seq, lnXW, vbuf, fkbuf, hvbuf,
                                                   Upkr, ucol, mask, g1, be1, bias, vx, flags, out);
  }
}